// Round 1
// baseline (666.527 us; speedup 1.0000x reference)
//
#include <hip/hip_runtime.h>
#include <hip/hip_bf16.h>

// Problem constants (from reference):
//   X_SIZE = 8,388,608  float32 gather table (32 MB, L3-resident)
//   NNZ    = 33,554,432 (ptr, csr) pairs; csr is SORTED
//   N_SEG  = 8,388,608  output segments (float32)
//
// out[csr[i]] += x[ptrs[i]]
//
// Strategy: per-thread contiguous 16-entry chunk; vectorized int4 index
// loads; gather all 16 values first (memory-level parallelism); run-length
// accumulate locally (csr sorted => ~4 entries/segment) and atomicAdd only
// at segment boundaries (~5 atomics / 16 entries).

#define THREADS 256
#define PER_THREAD 16

__global__ __launch_bounds__(THREADS) void SumLayer_gather_segsum(
    const float* __restrict__ x,
    const int*   __restrict__ ptrs,
    const int*   __restrict__ csr,
    float*       __restrict__ out)
{
    const long long base =
        ((long long)blockIdx.x * THREADS + threadIdx.x) * PER_THREAD;

    const int4* p4 = reinterpret_cast<const int4*>(ptrs + base);
    const int4* c4 = reinterpret_cast<const int4*>(csr + base);

    int p[PER_THREAD];
    int c[PER_THREAD];
#pragma unroll
    for (int k = 0; k < PER_THREAD / 4; ++k) {
        int4 a = p4[k];
        int4 b = c4[k];
        p[k * 4 + 0] = a.x; p[k * 4 + 1] = a.y;
        p[k * 4 + 2] = a.z; p[k * 4 + 3] = a.w;
        c[k * 4 + 0] = b.x; c[k * 4 + 1] = b.y;
        c[k * 4 + 2] = b.z; c[k * 4 + 3] = b.w;
    }

    // Issue all gathers before any consumption — maximize loads in flight.
    float v[PER_THREAD];
#pragma unroll
    for (int j = 0; j < PER_THREAD; ++j) {
        v[j] = x[p[j]];
    }

    // Run-length local accumulation over the sorted segment ids.
    float acc = v[0];
    int   cur = c[0];
#pragma unroll
    for (int j = 1; j < PER_THREAD; ++j) {
        if (c[j] == cur) {
            acc += v[j];
        } else {
            atomicAdd(out + cur, acc);
            cur = c[j];
            acc = v[j];
        }
    }
    atomicAdd(out + cur, acc);
}

extern "C" void kernel_launch(void* const* d_in, const int* in_sizes, int n_in,
                              void* d_out, int out_size, void* d_ws, size_t ws_size,
                              hipStream_t stream) {
    const float* x    = (const float*)d_in[0];
    const int*   ptrs = (const int*)d_in[1];
    const int*   csr  = (const int*)d_in[2];
    float*       out  = (float*)d_out;

    const int nnz = in_sizes[1];                      // 33,554,432
    const int total_threads = nnz / PER_THREAD;       // 2,097,152
    const int blocks = total_threads / THREADS;       // 8,192 (exact, no tail)

    // Segments with no entries must be zero; atomics accumulate on top.
    hipMemsetAsync(d_out, 0, (size_t)out_size * sizeof(float), stream);

    SumLayer_gather_segsum<<<blocks, THREADS, 0, stream>>>(x, ptrs, csr, out);
}

// Round 3
// 557.709 us; speedup vs baseline: 1.1951x; 1.1951x over previous
//
#include <hip/hip_runtime.h>
#include <hip/hip_bf16.h>

// out[csr[i]] += x[ptrs[i]]
//   X_SIZE = 8,388,608 f32 (32 MB, L3-resident), NNZ = 33,554,432, N_SEG = 8,388,608
//   csr is SORTED.
//
// Key structural facts exploited here:
//  - A block owns entries [b*4096, (b+1)*4096). Since csr is globally sorted,
//    every segment id strictly between csr[first] and csr[last] of this block
//    occurs ONLY in this block -> plain stores. Only the first and last
//    segment of the block can be shared with neighbor blocks -> atomicAdd.
//  - Block segment span ~ 4096/4 = 1024 (std ~32); LDS_SEGS=4096 gives
//    astronomically safe headroom, with an atomic fallback just in case.
//  - Index streams have zero reuse -> nontemporal loads (don't evict x from
//    L2); out stores are streaming -> nontemporal stores.

#define THREADS 256
#define PER_THREAD 16
#define ENTRIES_PER_BLOCK (THREADS * PER_THREAD)   // 4096
#define LDS_SEGS 4096                              // 16 KB LDS

typedef int  vint4 __attribute__((ext_vector_type(4)));   // native clang vector
                                                          // (nontemporal-load ok)

__global__ __launch_bounds__(THREADS) void SumLayer_gather_segsum_lds(
    const float* __restrict__ x,
    const int*   __restrict__ ptrs,
    const int*   __restrict__ csr,
    float*       __restrict__ out)
{
    __shared__ float seg[LDS_SEGS];

    const int tid = threadIdx.x;
    const long long blk_base = (long long)blockIdx.x * ENTRIES_PER_BLOCK;
    const long long base     = blk_base + (long long)tid * PER_THREAD;

    // Block's segment range (scalar, broadcast, L2-hot).
    const int seg_base = csr[blk_base];
    const int seg_last = csr[blk_base + ENTRIES_PER_BLOCK - 1];
    const int span     = seg_last - seg_base + 1;

    // Zero the LDS accumulator.
    for (int s = tid; s < LDS_SEGS; s += THREADS) seg[s] = 0.0f;

    // Vector index loads (nontemporal: pure streaming, keep L2 for x/out).
    const vint4* p4 = reinterpret_cast<const vint4*>(ptrs + base);
    const vint4* c4 = reinterpret_cast<const vint4*>(csr + base);
    int p[PER_THREAD];
    int c[PER_THREAD];
#pragma unroll
    for (int k = 0; k < PER_THREAD / 4; ++k) {
        vint4 a = __builtin_nontemporal_load(p4 + k);
        vint4 b = __builtin_nontemporal_load(c4 + k);
        p[k * 4 + 0] = a.x; p[k * 4 + 1] = a.y;
        p[k * 4 + 2] = a.z; p[k * 4 + 3] = a.w;
        c[k * 4 + 0] = b.x; c[k * 4 + 1] = b.y;
        c[k * 4 + 2] = b.z; c[k * 4 + 3] = b.w;
    }

    // Issue all gathers before consumption (MLP).
    float v[PER_THREAD];
#pragma unroll
    for (int j = 0; j < PER_THREAD; ++j) {
        v[j] = x[p[j]];
    }

    __syncthreads();   // LDS zeroing complete

    if (span <= LDS_SEGS) {
        // Run-length local reduction, then LDS atomics (cheap, ~2-way max).
        float acc = v[0];
        int   cur = c[0];
#pragma unroll
        for (int j = 1; j < PER_THREAD; ++j) {
            if (c[j] == cur) {
                acc += v[j];
            } else {
                atomicAdd(&seg[cur - seg_base], acc);
                cur = c[j];
                acc = v[j];
            }
        }
        atomicAdd(&seg[cur - seg_base], acc);

        __syncthreads();

        // Coalesced write-out. Interior segments are exclusively owned ->
        // plain nontemporal stores. Boundary segments (first/last) may be
        // shared with neighbor blocks -> global atomicAdd.
        for (int s = tid; s < span; s += THREADS) {
            const int   g   = seg_base + s;
            const float val = seg[s];
            if (s == 0 || g == seg_last) {
                if (val != 0.0f) atomicAdd(out + g, val);
            } else {
                __builtin_nontemporal_store(val, out + g);
            }
        }
    } else {
        // Fallback (statistically unreachable): direct global atomics.
        float acc = v[0];
        int   cur = c[0];
#pragma unroll
        for (int j = 1; j < PER_THREAD; ++j) {
            if (c[j] == cur) {
                acc += v[j];
            } else {
                atomicAdd(out + cur, acc);
                cur = c[j];
                acc = v[j];
            }
        }
        atomicAdd(out + cur, acc);
    }
}

extern "C" void kernel_launch(void* const* d_in, const int* in_sizes, int n_in,
                              void* d_out, int out_size, void* d_ws, size_t ws_size,
                              hipStream_t stream) {
    const float* x    = (const float*)d_in[0];
    const int*   ptrs = (const int*)d_in[1];
    const int*   csr  = (const int*)d_in[2];
    float*       out  = (float*)d_out;

    const int nnz    = in_sizes[1];                     // 33,554,432
    const int blocks = nnz / ENTRIES_PER_BLOCK;         // 8,192 (exact)

    // Segments outside any block's span (leading/trailing/gap segments)
    // must be zero; boundary atomics accumulate on top of zero.
    (void)hipMemsetAsync(d_out, 0, (size_t)out_size * sizeof(float), stream);

    SumLayer_gather_segsum_lds<<<blocks, THREADS, 0, stream>>>(x, ptrs, csr, out);
}